// Round 6
// baseline (597.078 us; speedup 1.0000x reference)
//
#include <hip/hip_runtime.h>
#include <math.h>

__device__ __forceinline__ float wave_sum(float v){
#pragma unroll
  for (int m = 1; m < 64; m <<= 1) v += __shfl_xor(v, m, 64);
  return v;
}

__device__ __forceinline__ unsigned short bf16_of(float a){
  unsigned ua = __float_as_uint(a);
  ua = (ua + 0x7FFFu + ((ua >> 16) & 1u)) >> 16;
  return (unsigned short)ua;
}
__device__ __forceinline__ unsigned pack_bf16(float a, float b){
  unsigned ua = __float_as_uint(a), ub = __float_as_uint(b);
  ua = (ua + 0x7FFFu + ((ua >> 16) & 1u)) >> 16;
  ub = (ub + 0x7FFFu + ((ub >> 16) & 1u)) >> 16;
  return ua | (ub << 16);
}
__device__ __forceinline__ float2 unpack_bf16(unsigned p){
  float2 r;
  r.x = __uint_as_float(p << 16);
  r.y = __uint_as_float(p & 0xFFFF0000u);
  return r;
}

// ---------------- CSR build (dst-major, self-loop first per node) ----------------
__global__ void k_deg_init(int* __restrict__ deg, int n){
  int i = blockIdx.x*blockDim.x + threadIdx.x;
  if (i < n) deg[i] = 1;          // self loop
}

__global__ void k_deg_count(const int* __restrict__ dst, int* __restrict__ deg, int e){
  int i = blockIdx.x*blockDim.x + threadIdx.x;
  if (i < e) atomicAdd(&deg[dst[i]], 1);
}

// ---- 3-phase parallel exclusive scan: deg[n] -> rowptr[n+1] ----
__global__ void k_scan_a(const int* __restrict__ deg, int* __restrict__ rowptr,
                         int* __restrict__ bsum, int n){
  __shared__ int sm[256];
  int i = blockIdx.x*256 + threadIdx.x;
  int v = (i < n) ? deg[i] : 0;
  sm[threadIdx.x] = v; __syncthreads();
#pragma unroll
  for (int off = 1; off < 256; off <<= 1){
    int t = (threadIdx.x >= off) ? sm[threadIdx.x - off] : 0;
    __syncthreads();
    sm[threadIdx.x] += t;
    __syncthreads();
  }
  if (i < n) rowptr[i] = sm[threadIdx.x] - v;   // exclusive within block
  if (threadIdx.x == 255) bsum[blockIdx.x] = sm[255];
}

__global__ void k_scan_b(int* __restrict__ bsum, int* __restrict__ rowptr, int nb, int n){
  __shared__ int sm[256];
  int t = threadIdx.x;
  int v = (t < nb) ? bsum[t] : 0;
  sm[t] = v; __syncthreads();
#pragma unroll
  for (int off = 1; off < 256; off <<= 1){
    int x = (t >= off) ? sm[t - off] : 0;
    __syncthreads();
    sm[t] += x;
    __syncthreads();
  }
  if (t < nb) bsum[t] = sm[t] - v;              // exclusive block offsets
  if (t == 255) rowptr[n] = sm[255];            // total
}

__global__ void k_scan_c(int* __restrict__ rowptr, const int* __restrict__ bsum, int n){
  int i = blockIdx.x*256 + threadIdx.x;
  if (i < n) rowptr[i] += bsum[blockIdx.x];
}

__global__ void k_selfloop(const int* __restrict__ rowptr, int* __restrict__ cursor,
                           int* __restrict__ csr, float* __restrict__ gc, int n){
  int i = blockIdx.x*blockDim.x + threadIdx.x;
  if (i < n){
    int r = rowptr[i];
    csr[r] = i;                   // self loop entry
    cursor[i] = r + 1;
  }
  if (i < 512) gc[i] = 0.f;       // zero the pooling accumulator
}

// scatter src into csr; record each edge's CSR rank with a COALESCED write
__global__ void k_scatter(const int* __restrict__ src, const int* __restrict__ dst,
                          int* __restrict__ cursor, int* __restrict__ csr,
                          int* __restrict__ epos, int e){
  int i = blockIdx.x*blockDim.x + threadIdx.x;
  if (i < e){
    int d = dst[i];
    int pos = atomicAdd(&cursor[d], 1);
    csr[pos] = src[i];
    epos[i] = pos - d - 1;        // rank in self-loop-free CSR (coalesced store)
  }
}

// ------- per-layer node transforms: xl(bf16), xr, residual(+bias); 8 nodes/wave -------
template<int K>
__global__ void k_node_transform(const float* __restrict__ h,
                                 const float* __restrict__ Wl, const float* __restrict__ bl,
                                 const float* __restrict__ Wr, const float* __restrict__ br,
                                 const float* __restrict__ Wres, const float* __restrict__ bias,
                                 unsigned short* __restrict__ xlh, float* __restrict__ xr,
                                 float* __restrict__ res, int n){
  int wq   = (blockIdx.x*blockDim.x + threadIdx.x) >> 6;
  int lane = threadIdx.x & 63;
  int n0 = wq * 8;
  if (n0 >= n) return;
  float hv[8];
#pragma unroll
  for (int j = 0; j < 8; ++j){
    int node = min(n0 + j, n - 1);
    hv[j] = (lane < K) ? h[(size_t)node*K + lane] : 0.f;
  }
  float aL[8], aR[8], aS[8];
  float blv = bl[lane], brv = br[lane], bsv = bias[lane];
#pragma unroll
  for (int j = 0; j < 8; ++j){ aL[j] = blv; aR[j] = brv; aS[j] = bsv; }
#pragma unroll 4
  for (int k = 0; k < K; ++k){
    float wl = Wl[k*64+lane], wr = Wr[k*64+lane], wsv = Wres[k*64+lane];
#pragma unroll
    for (int j = 0; j < 8; ++j){
      float hk = __shfl(hv[j], k, 64);
      aL[j] = fmaf(hk, wl,  aL[j]);
      aR[j] = fmaf(hk, wr,  aR[j]);
      aS[j] = fmaf(hk, wsv, aS[j]);
    }
  }
#pragma unroll
  for (int j = 0; j < 8; ++j){
    int node = n0 + j;
    if (node < n){
      size_t o = (size_t)node*64 + lane;
      xlh[o] = bf16_of(aL[j]);
      xr[o] = aR[j]; res[o] = aS[j];
    }
  }
}

// --- fused: edge softmax (online, 8 edges in flight, bf16 xl gathers) + LN + relu ---
// wave per node; 8 edge slots x 8 lanes (8 channels each, one uint4 per lane)
__global__ void k_gat_edge(const uint4* __restrict__ xl4, const float* __restrict__ xr,
                           const float* __restrict__ att,
                           const float* __restrict__ lng, const float* __restrict__ lnb,
                           const int* __restrict__ rowptr, const int* __restrict__ csr,
                           float* __restrict__ hio /* in: residual, out: h_next */, int n){
  int node = (blockIdx.x*blockDim.x + threadIdx.x) >> 6;
  int lane = threadIdx.x & 63;
  if (node >= n) return;
  int sub = lane >> 3;          // edge slot (0..7)
  int l   = lane & 7;           // channels 8l .. 8l+7
  size_t base = (size_t)node*64 + 8*l;
  float4 xr0 = *(const float4*)&xr[base];
  float4 xr1 = *(const float4*)&xr[base+4];
  float4 at0 = *(const float4*)&att[8*l];
  float4 at1 = *(const float4*)&att[8*l+4];
  int p0 = rowptr[node], p1 = rowptr[node+1];
  int deg = p1 - p0;            // >= 1 (self loop)
  int sreg = csr[p0 + min(lane, deg-1)];   // cache first 64 neighbor ids in regs
  int rounds = (deg + 7) >> 3;
  float m = -1e30f, dsum = 0.f;
  float c0=0.f,c1=0.f,c2=0.f,c3=0.f,c4=0.f,c5=0.f,c6=0.f,c7=0.f;
  // stage 0 prefetch
  int e = sub;
  bool vcur = e < deg;
  int scur = __shfl(sreg, vcur ? e : 0, 64);
  uint4 xcur = xl4[(size_t)scur*8 + l];
  for (int r = 0; r < rounds; ++r){
    int en = 8*(r+1) + sub;
    bool vn = en < deg;
    int sn;
    if (en < 64) sn = __shfl(sreg, vn ? en : 0, 64);
    else         sn = csr[p0 + (vn ? en : 0)];
    uint4 xnxt = xcur;
    if (r + 1 < rounds) xnxt = xl4[(size_t)sn*8 + l];
    // compute current
    float2 u0 = unpack_bf16(xcur.x), u1 = unpack_bf16(xcur.y);
    float2 u2 = unpack_bf16(xcur.z), u3 = unpack_bf16(xcur.w);
    float v0 = u0.x + xr0.x, v1 = u0.y + xr0.y, v2 = u1.x + xr0.z, v3 = u1.y + xr0.w;
    float v4 = u2.x + xr1.x, v5 = u2.y + xr1.y, v6 = u3.x + xr1.z, v7 = u3.y + xr1.w;
    v0 = v0 > 0.f ? v0 : 0.2f*v0;  v1 = v1 > 0.f ? v1 : 0.2f*v1;
    v2 = v2 > 0.f ? v2 : 0.2f*v2;  v3 = v3 > 0.f ? v3 : 0.2f*v3;
    v4 = v4 > 0.f ? v4 : 0.2f*v4;  v5 = v5 > 0.f ? v5 : 0.2f*v5;
    v6 = v6 > 0.f ? v6 : 0.2f*v6;  v7 = v7 > 0.f ? v7 : 0.2f*v7;
    float partial = fmaf(v0, at0.x, fmaf(v1, at0.y, fmaf(v2, at0.z, v3*at0.w)));
    partial = fmaf(v4, at1.x, fmaf(v5, at1.y, fmaf(v6, at1.z, fmaf(v7, at1.w, partial))));
#pragma unroll
    for (int mm = 1; mm < 8; mm <<= 1) partial += __shfl_xor(partial, mm, 64);
    float logit = vcur ? partial : -3e30f;
    float nm = fmaxf(m, logit);
    float sc = __expf(m - nm);
    float w  = __expf(logit - nm);
    dsum = fmaf(dsum, sc, w);
    c0 = fmaf(c0, sc, w*u0.x); c1 = fmaf(c1, sc, w*u0.y);
    c2 = fmaf(c2, sc, w*u1.x); c3 = fmaf(c3, sc, w*u1.y);
    c4 = fmaf(c4, sc, w*u2.x); c5 = fmaf(c5, sc, w*u2.y);
    c6 = fmaf(c6, sc, w*u3.x); c7 = fmaf(c7, sc, w*u3.y);
    m = nm;
    xcur = xnxt; vcur = vn;
  }
  // merge the 8 sub-groups' online-softmax states
#pragma unroll
  for (int off = 8; off < 64; off <<= 1){
    float mo = __shfl_xor(m, off, 64);
    float M  = fmaxf(m, mo);
    float sc = __expf(m - M);
    dsum *= sc; c0 *= sc; c1 *= sc; c2 *= sc; c3 *= sc;
    c4 *= sc; c5 *= sc; c6 *= sc; c7 *= sc;
    m = M;
    dsum += __shfl_xor(dsum, off, 64);
    c0 += __shfl_xor(c0, off, 64); c1 += __shfl_xor(c1, off, 64);
    c2 += __shfl_xor(c2, off, 64); c3 += __shfl_xor(c3, off, 64);
    c4 += __shfl_xor(c4, off, 64); c5 += __shfl_xor(c5, off, 64);
    c6 += __shfl_xor(c6, off, 64); c7 += __shfl_xor(c7, off, 64);
  }
  float4 r0 = *(const float4*)&hio[base];
  float4 r1 = *(const float4*)&hio[base+4];
  float inv = 1.f / dsum;
  float o0 = fmaf(c0, inv, r0.x), o1 = fmaf(c1, inv, r0.y);
  float o2 = fmaf(c2, inv, r0.z), o3 = fmaf(c3, inv, r0.w);
  float o4 = fmaf(c4, inv, r1.x), o5 = fmaf(c5, inv, r1.y);
  float o6 = fmaf(c6, inv, r1.z), o7 = fmaf(c7, inv, r1.w);
  // layernorm over 64 channels; each channel appears 8x across the wave
  float mean = wave_sum(o0+o1+o2+o3+o4+o5+o6+o7) * (1.f/512.f);
  float d0=o0-mean, d1=o1-mean, d2=o2-mean, d3=o3-mean;
  float d4=o4-mean, d5=o5-mean, d6=o6-mean, d7=o7-mean;
  float var = wave_sum(fmaf(d0,d0,fmaf(d1,d1,fmaf(d2,d2,fmaf(d3,d3,
              fmaf(d4,d4,fmaf(d5,d5,fmaf(d6,d6,d7*d7))))))) ) * (1.f/512.f);
  float rstd = rsqrtf(var + 1e-5f);
  if (sub == 0){
    float4 g0v = *(const float4*)&lng[8*l];
    float4 g1v = *(const float4*)&lng[8*l+4];
    float4 b0v = *(const float4*)&lnb[8*l];
    float4 b1v = *(const float4*)&lnb[8*l+4];
    float4 w0, w1;
    w0.x = fmaxf(fmaf(d0*rstd, g0v.x, b0v.x), 0.f);
    w0.y = fmaxf(fmaf(d1*rstd, g0v.y, b0v.y), 0.f);
    w0.z = fmaxf(fmaf(d2*rstd, g0v.z, b0v.z), 0.f);
    w0.w = fmaxf(fmaf(d3*rstd, g0v.w, b0v.w), 0.f);
    w1.x = fmaxf(fmaf(d4*rstd, g1v.x, b1v.x), 0.f);
    w1.y = fmaxf(fmaf(d5*rstd, g1v.y, b1v.y), 0.f);
    w1.z = fmaxf(fmaf(d6*rstd, g1v.z, b1v.z), 0.f);
    w1.w = fmaxf(fmaf(d7*rstd, g1v.w, b1v.w), 0.f);
    *(float4*)&hio[base] = w0;
    *(float4*)&hio[base+4] = w1;
  }
}

// ---------------- global add pool (batch is sorted) ----------------
__global__ void k_pool(const float* __restrict__ h, const int* __restrict__ batch,
                       float* __restrict__ gc, int n){
  int wid  = (blockIdx.x*blockDim.x + threadIdx.x) >> 6;
  int lane = threadIdx.x & 63;
  int n0 = wid*64;
  if (n0 >= n) return;
  int n1 = min(n0+64, n);
  int curg = batch[n0];
  float s = 0.f;
  for (int i = n0; i < n1; ++i){
    int g = batch[i];
    if (g != curg){ atomicAdd(&gc[curg*64+lane], s); s = 0.f; curg = g; }
    s += h[(size_t)i*64 + lane];
  }
  atomicAdd(&gc[curg*64+lane], s);
}

// ---------------- G[g] = gc[g] @ W1c + b1 ----------------
__global__ void k_graph_proj(const float* __restrict__ gc, const float* __restrict__ W1,
                             const float* __restrict__ b1, float* __restrict__ G){
  int g = threadIdx.x >> 7;       // 8 graphs x 128 cols = 1024 threads
  int j = threadIdx.x & 127;
  float a = b1[j];
#pragma unroll 8
  for (int k = 0; k < 64; ++k) a = fmaf(gc[g*64+k], W1[(128+k)*128 + j], a);
  G[g*128 + j] = a;
}

// -------- A = nr @ W1a ; B = nr @ W1b (bf16 packed, 8 nodes per wave) --------
__global__ void k_node_proj(const float* __restrict__ nr, const float* __restrict__ W1,
                            unsigned* __restrict__ Au, unsigned* __restrict__ Bu, int n){
  int wq   = (blockIdx.x*blockDim.x + threadIdx.x) >> 6;
  int lane = threadIdx.x & 63;
  int n0 = wq * 8;
  if (n0 >= n) return;
  float hv[8];
#pragma unroll
  for (int j = 0; j < 8; ++j){
    int node = min(n0 + j, n - 1);
    hv[j] = nr[(size_t)node*64 + lane];
  }
  float a0[8], a1[8], b0[8], b1v[8];
#pragma unroll
  for (int j = 0; j < 8; ++j){ a0[j]=0.f; a1[j]=0.f; b0[j]=0.f; b1v[j]=0.f; }
#pragma unroll 4
  for (int k = 0; k < 64; ++k){
    float2 wa = *(const float2*)&W1[k*128 + 2*lane];
    float2 wb = *(const float2*)&W1[(64+k)*128 + 2*lane];
#pragma unroll
    for (int j = 0; j < 8; ++j){
      float hk = __shfl(hv[j], k, 64);
      a0[j]  = fmaf(hk, wa.x, a0[j]);
      a1[j]  = fmaf(hk, wa.y, a1[j]);
      b0[j]  = fmaf(hk, wb.x, b0[j]);
      b1v[j] = fmaf(hk, wb.y, b1v[j]);
    }
  }
#pragma unroll
  for (int j = 0; j < 8; ++j){
    int node = n0 + j;
    if (node < n){
      size_t o = (size_t)node*64 + lane;
      Au[o] = pack_bf16(a0[j], a1[j]);
      Bu[o] = pack_bf16(b0[j], b1v[j]);
    }
  }
}

// -- final per-edge MLP, dst-major: B[d] once, A[s] gathered, tmp written coalesced --
// wave per node; 8 edge slots x 8 lanes (16 channels = 2 uint4 per lane)
__global__ void k_edge_out_csr(const uint4* __restrict__ Au4, const uint4* __restrict__ Bu4,
                               const float* __restrict__ G,
                               const int* __restrict__ rowptr, const int* __restrict__ csr,
                               const int* __restrict__ batch,
                               const float* __restrict__ W2, const float* __restrict__ b2,
                               float* __restrict__ tmp, int n){
  int node = (blockIdx.x*blockDim.x + threadIdx.x) >> 6;
  int lane = threadIdx.x & 63;
  if (node >= n) return;
  int sub = lane >> 3;
  int l   = lane & 7;             // dwords 8l..8l+7 = channels 16l..16l+15
  int p0 = rowptr[node];
  int deg2 = rowptr[node+1] - p0 - 1;      // excludes self loop
  if (deg2 <= 0) return;
  uint4 bA = Bu4[(size_t)node*16 + 2*l];
  uint4 bB = Bu4[(size_t)node*16 + 2*l + 1];
  float2 b0 = unpack_bf16(bA.x), b1 = unpack_bf16(bA.y);
  float2 b2p = unpack_bf16(bA.z), b3 = unpack_bf16(bA.w);
  float2 b4 = unpack_bf16(bB.x), b5 = unpack_bf16(bB.y);
  float2 b6 = unpack_bf16(bB.z), b7 = unpack_bf16(bB.w);
  float4 w0 = *(const float4*)&W2[16*l];
  float4 w1 = *(const float4*)&W2[16*l + 4];
  float4 w2 = *(const float4*)&W2[16*l + 8];
  float4 w3 = *(const float4*)&W2[16*l + 12];
  float b2v = b2[0];
  int rbase = p0 - node;          // rank base in self-loop-free CSR
  int rounds = (deg2 + 7) >> 3;
  // stage 0 prefetch
  int e = sub;
  bool vcur = e < deg2;
  int scur = csr[p0 + 1 + (vcur ? e : 0)];
  uint4 aA = Au4[(size_t)scur*16 + 2*l];
  uint4 aB = Au4[(size_t)scur*16 + 2*l + 1];
  for (int r = 0; r < rounds; ++r){
    int en = 8*(r+1) + sub;
    bool vn = en < deg2;
    int sn = csr[p0 + 1 + (vn ? en : 0)];
    uint4 nA = aA, nB = aB;
    if (r + 1 < rounds){
      nA = Au4[(size_t)sn*16 + 2*l];
      nB = Au4[(size_t)sn*16 + 2*l + 1];
    }
    // compute current edge
    int g = batch[scur];
    const float* Gp = &G[g*128 + 16*l];
    float4 g0 = *(const float4*)Gp;
    float4 g1 = *(const float4*)(Gp + 4);
    float4 g2 = *(const float4*)(Gp + 8);
    float4 g3 = *(const float4*)(Gp + 12);
    float2 a0 = unpack_bf16(aA.x), a1 = unpack_bf16(aA.y);
    float2 a2 = unpack_bf16(aA.z), a3 = unpack_bf16(aA.w);
    float2 a4 = unpack_bf16(aB.x), a5 = unpack_bf16(aB.y);
    float2 a6 = unpack_bf16(aB.z), a7 = unpack_bf16(aB.w);
    float part;
    part = fmaxf(a0.x + b0.x + g0.x, 0.f) * w0.x;
    part = fmaf(fmaxf(a0.y + b0.y + g0.y, 0.f), w0.y, part);
    part = fmaf(fmaxf(a1.x + b1.x + g0.z, 0.f), w0.z, part);
    part = fmaf(fmaxf(a1.y + b1.y + g0.w, 0.f), w0.w, part);
    part = fmaf(fmaxf(a2.x + b2p.x + g1.x, 0.f), w1.x, part);
    part = fmaf(fmaxf(a2.y + b2p.y + g1.y, 0.f), w1.y, part);
    part = fmaf(fmaxf(a3.x + b3.x + g1.z, 0.f), w1.z, part);
    part = fmaf(fmaxf(a3.y + b3.y + g1.w, 0.f), w1.w, part);
    part = fmaf(fmaxf(a4.x + b4.x + g2.x, 0.f), w2.x, part);
    part = fmaf(fmaxf(a4.y + b4.y + g2.y, 0.f), w2.y, part);
    part = fmaf(fmaxf(a5.x + b5.x + g2.z, 0.f), w2.z, part);
    part = fmaf(fmaxf(a5.y + b5.y + g2.w, 0.f), w2.w, part);
    part = fmaf(fmaxf(a6.x + b6.x + g3.x, 0.f), w3.x, part);
    part = fmaf(fmaxf(a6.y + b6.y + g3.y, 0.f), w3.y, part);
    part = fmaf(fmaxf(a7.x + b7.x + g3.z, 0.f), w3.z, part);
    part = fmaf(fmaxf(a7.y + b7.y + g3.w, 0.f), w3.w, part);
#pragma unroll
    for (int mm = 1; mm < 8; mm <<= 1) part += __shfl_xor(part, mm, 64);
    if (l == 0 && vcur) tmp[rbase + 8*r + sub] = part + b2v;   // coalesced (CSR order)
    aA = nA; aB = nB; vcur = vn; scur = sn;
  }
}

// ---- out[i] = tmp[epos[i]] : coalesced read of epos + L2-resident gather ----
__global__ void k_remap(const float* __restrict__ tmp, const int* __restrict__ epos,
                        float* __restrict__ out, int e){
  int i = blockIdx.x*blockDim.x + threadIdx.x;
  if (i < e) out[i] = tmp[epos[i]];
}

extern "C" void kernel_launch(void* const* d_in, const int* in_sizes, int n_in,
                              void* d_out, int out_size, void* d_ws, size_t ws_size,
                              hipStream_t stream){
  const float* x     = (const float*)d_in[0];
  const int*   ei    = (const int*)d_in[1];
  const int*   batch = (const int*)d_in[2];
  const int N = in_sizes[2];
  const int E = in_sizes[1] / 2;
  const int* src = ei;
  const int* dst = ei + E;

  unsigned* W = (unsigned*)d_ws;
  const size_t N32 = (size_t)N * 32;
  const size_t N64 = (size_t)N * 64;
  // dword layout: [xl bf16: N32][xr: N64][hE: N64][hD: N64] | ints | gc/G/bsum/tmp
  unsigned short* xlh = (unsigned short*)W;          // N x 64 bf16
  float* xr = (float*)(W + N32);
  float* hE = (float*)(W + N32 + N64);
  float* hD = (float*)(W + N32 + 2*N64);
  // readout aliases (xl/xr/hE dead by then; hD untouched)
  unsigned* Au = W;                                  // N x 64 dwords
  unsigned* Bu = W + N64;                            // N x 64 dwords (ends < hD)
  int* rowptr = (int*)(W + N32 + 3*N64);             // N+2
  int* cursor = rowptr + (N + 2);                    // N
  int* csr    = cursor + N;                          // N + E
  int* epos   = csr + (N + E);                       // E
  float* gc   = (float*)(epos + E);                  // 8*64
  float* G    = gc + 512;                            // 8*128
  int* bsum   = (int*)(G + 1024);                    // ceil(N/256)
  float* tmp  = (float*)(bsum + 256);                // E floats (CSR-ordered results)

  const int NB = (N + 255) / 256;

  // ---- CSR build (once, reused by all 3 layers + edge MLP) ----
  k_deg_init <<<(N+255)/256, 256, 0, stream>>>(cursor, N);
  k_deg_count<<<(E+255)/256, 256, 0, stream>>>(dst, cursor, E);
  k_scan_a   <<<NB, 256, 0, stream>>>(cursor, rowptr, bsum, N);
  k_scan_b   <<<1, 256, 0, stream>>>(bsum, rowptr, NB, N);
  k_scan_c   <<<NB, 256, 0, stream>>>(rowptr, bsum, N);
  k_selfloop <<<(N+255)/256, 256, 0, stream>>>(rowptr, cursor, csr, gc, N);
  k_scatter  <<<(E+255)/256, 256, 0, stream>>>(src, dst, cursor, csr, epos, E);

  // ---- 3 GATv2 layers ----
  const float* h = x;
  float* hn = hD;
  for (int l = 0; l < 3; ++l){
    const float* Wl   = (const float*)d_in[3 + 9*l + 0];
    const float* bl   = (const float*)d_in[3 + 9*l + 1];
    const float* Wr   = (const float*)d_in[3 + 9*l + 2];
    const float* br   = (const float*)d_in[3 + 9*l + 3];
    const float* att  = (const float*)d_in[3 + 9*l + 4];
    const float* Wres = (const float*)d_in[3 + 9*l + 5];
    const float* bias = (const float*)d_in[3 + 9*l + 6];
    const float* lng  = (const float*)d_in[3 + 9*l + 7];
    const float* lnb  = (const float*)d_in[3 + 9*l + 8];
    if (l == 0)
      k_node_transform<32><<<(N+31)/32, 256, 0, stream>>>(h, Wl, bl, Wr, br, Wres, bias, xlh, xr, hn, N);
    else
      k_node_transform<64><<<(N+31)/32, 256, 0, stream>>>(h, Wl, bl, Wr, br, Wres, bias, xlh, xr, hn, N);
    k_gat_edge<<<(N+3)/4, 256, 0, stream>>>((const uint4*)xlh, xr, att, lng, lnb, rowptr, csr, hn, N);
    h = hn;
    hn = (l == 0) ? hE : hD;   // L0->hD, L1->hE, L2->hD ; final node_repr = hD
  }

  // ---- readout ----
  const float* W1 = (const float*)d_in[30];
  const float* b1 = (const float*)d_in[31];
  const float* W2 = (const float*)d_in[32];
  const float* b2 = (const float*)d_in[33];

  int pool_waves = (N + 63) / 64;
  k_pool      <<<(pool_waves+3)/4, 256, 0, stream>>>(hD, batch, gc, N);
  k_graph_proj<<<1, 1024, 0, stream>>>(gc, W1, b1, G);
  k_node_proj <<<(N+31)/32, 256, 0, stream>>>(hD, W1, Au, Bu, N);
  k_edge_out_csr<<<(N+3)/4, 256, 0, stream>>>((const uint4*)Au, (const uint4*)Bu, G,
                                              rowptr, csr, batch, W2, b2, tmp, N);
  k_remap     <<<(E+255)/256, 256, 0, stream>>>(tmp, epos, (float*)d_out, E);
}

// Round 7
// 575.493 us; speedup vs baseline: 1.0375x; 1.0375x over previous
//
#include <hip/hip_runtime.h>
#include <math.h>

typedef float floatx2 __attribute__((ext_vector_type(2)));

__device__ __forceinline__ float wave_sum(float v){
#pragma unroll
  for (int m = 1; m < 64; m <<= 1) v += __shfl_xor(v, m, 64);
  return v;
}

__device__ __forceinline__ unsigned short bf16_of(float a){
  unsigned ua = __float_as_uint(a);
  ua = (ua + 0x7FFFu + ((ua >> 16) & 1u)) >> 16;
  return (unsigned short)ua;
}
__device__ __forceinline__ unsigned pack_bf16(float a, float b){
  unsigned ua = __float_as_uint(a), ub = __float_as_uint(b);
  ua = (ua + 0x7FFFu + ((ua >> 16) & 1u)) >> 16;
  ub = (ub + 0x7FFFu + ((ub >> 16) & 1u)) >> 16;
  return ua | (ub << 16);
}
__device__ __forceinline__ float2 unpack_bf16(unsigned p){
  float2 r;
  r.x = __uint_as_float(p << 16);
  r.y = __uint_as_float(p & 0xFFFF0000u);
  return r;
}

// ---------------- CSR build (dst-major, self-loop first per node) ----------------
__global__ void k_deg_count(const int* __restrict__ dst, int* __restrict__ deg, int e){
  int i = blockIdx.x*blockDim.x + threadIdx.x;
  if (i < e) atomicAdd(&deg[dst[i]], 1);
}

// ---- parallel exclusive scan of (deg[i]+1) -> rowptr ----
__global__ void k_scan_a(const int* __restrict__ deg, int* __restrict__ rowptr,
                         int* __restrict__ bsum, int n){
  __shared__ int sm[256];
  int i = blockIdx.x*256 + threadIdx.x;
  int v = (i < n) ? (deg[i] + 1) : 0;   // +1 self loop
  sm[threadIdx.x] = v; __syncthreads();
#pragma unroll
  for (int off = 1; off < 256; off <<= 1){
    int t = (threadIdx.x >= off) ? sm[threadIdx.x - off] : 0;
    __syncthreads();
    sm[threadIdx.x] += t;
    __syncthreads();
  }
  if (i < n) rowptr[i] = sm[threadIdx.x] - v;   // exclusive within block
  if (threadIdx.x == 255) bsum[blockIdx.x] = sm[255];
}

__global__ void k_scan_b(int* __restrict__ bsum, int* __restrict__ rowptr, int nb, int n){
  __shared__ int sm[256];
  int t = threadIdx.x;
  int v = (t < nb) ? bsum[t] : 0;
  sm[t] = v; __syncthreads();
#pragma unroll
  for (int off = 1; off < 256; off <<= 1){
    int x = (t >= off) ? sm[t - off] : 0;
    __syncthreads();
    sm[t] += x;
    __syncthreads();
  }
  if (t < nb) bsum[t] = sm[t] - v;              // exclusive block offsets
  if (t == 255) rowptr[n] = sm[255];            // total
}

// fused: add block offset, write self-loop entry, init cursor, zero gc
__global__ void k_scan_c_selfloop(int* __restrict__ rowptr, const int* __restrict__ bsum,
                                  int* __restrict__ cursor, int* __restrict__ csr,
                                  float* __restrict__ gc, int n){
  int i = blockIdx.x*256 + threadIdx.x;
  if (i < n){
    int r = rowptr[i] + bsum[blockIdx.x];
    rowptr[i] = r;
    csr[r] = i;                   // self loop entry
    cursor[i] = r + 1;
  }
  if (blockIdx.x == 0){
    gc[threadIdx.x] = 0.f;
    gc[threadIdx.x + 256] = 0.f;
  }
}

// scatter src into csr; record each edge's CSR rank with a COALESCED write
__global__ void k_scatter(const int* __restrict__ src, const int* __restrict__ dst,
                          int* __restrict__ cursor, int* __restrict__ csr,
                          int* __restrict__ epos, int e){
  int i = blockIdx.x*blockDim.x + threadIdx.x;
  if (i < e){
    int d = dst[i];
    int pos = atomicAdd(&cursor[d], 1);
    csr[pos] = src[i];
    epos[i] = pos - d - 1;        // rank in self-loop-free CSR (coalesced store)
  }
}

// ------- per-layer node transforms: xl(bf16), xr, residual(+bias); 8 nodes/wave -------
template<int K>
__global__ void k_node_transform(const float* __restrict__ h,
                                 const float* __restrict__ Wl, const float* __restrict__ bl,
                                 const float* __restrict__ Wr, const float* __restrict__ br,
                                 const float* __restrict__ Wres, const float* __restrict__ bias,
                                 unsigned short* __restrict__ xlh, float* __restrict__ xr,
                                 float* __restrict__ res, int n){
  int wq   = (blockIdx.x*blockDim.x + threadIdx.x) >> 6;
  int lane = threadIdx.x & 63;
  int n0 = wq * 8;
  if (n0 >= n) return;
  float hv[8];
#pragma unroll
  for (int j = 0; j < 8; ++j){
    int node = min(n0 + j, n - 1);
    hv[j] = (lane < K) ? h[(size_t)node*K + lane] : 0.f;
  }
  float aL[8], aR[8], aS[8];
  float blv = bl[lane], brv = br[lane], bsv = bias[lane];
#pragma unroll
  for (int j = 0; j < 8; ++j){ aL[j] = blv; aR[j] = brv; aS[j] = bsv; }
#pragma unroll 4
  for (int k = 0; k < K; ++k){
    float wl = Wl[k*64+lane], wr = Wr[k*64+lane], wsv = Wres[k*64+lane];
#pragma unroll
    for (int j = 0; j < 8; ++j){
      float hk = __shfl(hv[j], k, 64);
      aL[j] = fmaf(hk, wl,  aL[j]);
      aR[j] = fmaf(hk, wr,  aR[j]);
      aS[j] = fmaf(hk, wsv, aS[j]);
    }
  }
#pragma unroll
  for (int j = 0; j < 8; ++j){
    int node = n0 + j;
    if (node < n){
      size_t o = (size_t)node*64 + lane;
      xlh[o] = bf16_of(aL[j]);
      xr[o] = aR[j]; res[o] = aS[j];
    }
  }
}

// --- fused: edge softmax (online, 4 edges in flight, bf16 xl gathers) + LN + relu ---
__global__ void k_gat_edge(const unsigned* __restrict__ xl_u, const float* __restrict__ xr,
                           const float* __restrict__ att,
                           const float* __restrict__ lng, const float* __restrict__ lnb,
                           const int* __restrict__ rowptr, const int* __restrict__ csr,
                           float* __restrict__ hio /* in: residual, out: h_next */, int n){
  int node = (blockIdx.x*blockDim.x + threadIdx.x) >> 6;
  int lane = threadIdx.x & 63;
  if (node >= n) return;
  int sub = lane >> 4;          // edge slot (0..3)
  int l   = lane & 15;          // channels 4l .. 4l+3
  size_t base = (size_t)node*64 + 4*l;
  float4 xrv  = *(const float4*)&xr[base];
  float4 attv = *(const float4*)&att[4*l];
  int p0 = rowptr[node], p1 = rowptr[node+1];
  int deg = p1 - p0;            // >= 1 (self loop)
  int sreg = csr[p0 + min(lane, deg-1)];   // cache first 64 neighbor ids in regs
  int rounds = (deg + 3) >> 2;
  float m = -1e30f, dsum = 0.f;
  float a0=0.f, a1=0.f, a2=0.f, a3=0.f;
  // stage 0 prefetch
  int e = sub;
  bool vcur = e < deg;
  int scur = __shfl(sreg, vcur ? e : 0, 64);
  uint2 xcur = *(const uint2*)&xl_u[(size_t)scur*32 + 2*l];
  for (int r = 0; r < rounds; ++r){
    // prefetch next round's rows (independent of this round's compute)
    int en = 4*(r+1) + sub;
    bool vn = en < deg;
    int sn;
    if (en < 64) sn = __shfl(sreg, vn ? en : 0, 64);
    else         sn = csr[p0 + (vn ? en : 0)];
    uint2 xnxt = xcur;
    if (r + 1 < rounds) xnxt = *(const uint2*)&xl_u[(size_t)sn*32 + 2*l];
    // compute current
    float2 p01 = unpack_bf16(xcur.x);
    float2 p23 = unpack_bf16(xcur.y);
    float vx = p01.x + xrv.x, vy = p01.y + xrv.y;
    float vz = p23.x + xrv.z, vw = p23.y + xrv.w;
    vx = vx > 0.f ? vx : 0.2f*vx;  vy = vy > 0.f ? vy : 0.2f*vy;
    vz = vz > 0.f ? vz : 0.2f*vz;  vw = vw > 0.f ? vw : 0.2f*vw;
    float partial = fmaf(vx, attv.x, fmaf(vy, attv.y, fmaf(vz, attv.z, vw*attv.w)));
#pragma unroll
    for (int mm = 1; mm < 16; mm <<= 1) partial += __shfl_xor(partial, mm, 64);
    float logit = vcur ? partial : -3e30f;
    float nm = fmaxf(m, logit);
    float sc = __expf(m - nm);
    float w  = __expf(logit - nm);
    dsum = fmaf(dsum, sc, w);
    a0 = fmaf(a0, sc, w*p01.x);
    a1 = fmaf(a1, sc, w*p01.y);
    a2 = fmaf(a2, sc, w*p23.x);
    a3 = fmaf(a3, sc, w*p23.y);
    m = nm;
    xcur = xnxt; vcur = vn;
  }
  // merge the 4 sub-groups' online-softmax states (xor 16, then xor 32)
#pragma unroll
  for (int off = 16; off < 64; off <<= 1){
    float mo = __shfl_xor(m, off, 64);
    float M  = fmaxf(m, mo);
    float sc = __expf(m - M);
    dsum *= sc; a0 *= sc; a1 *= sc; a2 *= sc; a3 *= sc;
    m = M;
    dsum += __shfl_xor(dsum, off, 64);
    a0 += __shfl_xor(a0, off, 64);
    a1 += __shfl_xor(a1, off, 64);
    a2 += __shfl_xor(a2, off, 64);
    a3 += __shfl_xor(a3, off, 64);
  }
  float4 resv = *(const float4*)&hio[base];
  float inv = 1.f / dsum;
  float ox = fmaf(a0, inv, resv.x);
  float oy = fmaf(a1, inv, resv.y);
  float oz = fmaf(a2, inv, resv.z);
  float ow = fmaf(a3, inv, resv.w);
  // layernorm over 64 channels; each channel appears 4x across the wave
  float mean = wave_sum(ox + oy + oz + ow) * (1.f/256.f);
  float dx = ox - mean, dy = oy - mean, dz = oz - mean, dw = ow - mean;
  float var = wave_sum(fmaf(dx,dx, fmaf(dy,dy, fmaf(dz,dz, dw*dw)))) * (1.f/256.f);
  float rstd = rsqrtf(var + 1e-5f);
  if (sub == 0){
    float4 lg = *(const float4*)&lng[4*l];
    float4 lb = *(const float4*)&lnb[4*l];
    float4 out;
    out.x = fmaxf(fmaf(dx*rstd, lg.x, lb.x), 0.f);
    out.y = fmaxf(fmaf(dy*rstd, lg.y, lb.y), 0.f);
    out.z = fmaxf(fmaf(dz*rstd, lg.z, lb.z), 0.f);
    out.w = fmaxf(fmaf(dw*rstd, lg.w, lb.w), 0.f);
    *(float4*)&hio[base] = out;
  }
}

// ---------------- global add pool (batch is sorted) ----------------
__global__ void k_pool(const float* __restrict__ h, const int* __restrict__ batch,
                       float* __restrict__ gc, int n){
  int wid  = (blockIdx.x*blockDim.x + threadIdx.x) >> 6;
  int lane = threadIdx.x & 63;
  int n0 = wid*64;
  if (n0 >= n) return;
  int n1 = min(n0+64, n);
  int curg = batch[n0];
  float s = 0.f;
  for (int i = n0; i < n1; ++i){
    int g = batch[i];
    if (g != curg){ atomicAdd(&gc[curg*64+lane], s); s = 0.f; curg = g; }
    s += h[(size_t)i*64 + lane];
  }
  atomicAdd(&gc[curg*64+lane], s);
}

// ---------------- G[g] = gc[g] @ W1c + b1 ----------------
__global__ void k_graph_proj(const float* __restrict__ gc, const float* __restrict__ W1,
                             const float* __restrict__ b1, float* __restrict__ G){
  int g = threadIdx.x >> 7;       // 8 graphs x 128 cols = 1024 threads
  int j = threadIdx.x & 127;
  float a = b1[j];
#pragma unroll 8
  for (int k = 0; k < 64; ++k) a = fmaf(gc[g*64+k], W1[(128+k)*128 + j], a);
  G[g*128 + j] = a;
}

// ---- A = nr @ W1a (fp8 packed) ; B = nr @ W1b (bf16 packed); 8 nodes per wave ----
__global__ void k_node_proj(const float* __restrict__ nr, const float* __restrict__ W1,
                            unsigned short* __restrict__ Au16, unsigned* __restrict__ Bu, int n){
  int wq   = (blockIdx.x*blockDim.x + threadIdx.x) >> 6;
  int lane = threadIdx.x & 63;
  int n0 = wq * 8;
  if (n0 >= n) return;
  float hv[8];
#pragma unroll
  for (int j = 0; j < 8; ++j){
    int node = min(n0 + j, n - 1);
    hv[j] = nr[(size_t)node*64 + lane];
  }
  float a0[8], a1[8], b0[8], b1v[8];
#pragma unroll
  for (int j = 0; j < 8; ++j){ a0[j]=0.f; a1[j]=0.f; b0[j]=0.f; b1v[j]=0.f; }
#pragma unroll 4
  for (int k = 0; k < 64; ++k){
    float2 wa = *(const float2*)&W1[k*128 + 2*lane];
    float2 wb = *(const float2*)&W1[(64+k)*128 + 2*lane];
#pragma unroll
    for (int j = 0; j < 8; ++j){
      float hk = __shfl(hv[j], k, 64);
      a0[j]  = fmaf(hk, wa.x, a0[j]);
      a1[j]  = fmaf(hk, wa.y, a1[j]);
      b0[j]  = fmaf(hk, wb.x, b0[j]);
      b1v[j] = fmaf(hk, wb.y, b1v[j]);
    }
  }
#pragma unroll
  for (int j = 0; j < 8; ++j){
    int node = n0 + j;
    if (node < n){
      size_t o = (size_t)node*64 + lane;
      Au16[o] = (unsigned short)__builtin_amdgcn_cvt_pk_fp8_f32(a0[j], a1[j], 0, false);
      Bu[o] = pack_bf16(b0[j], b1v[j]);
    }
  }
}

// -- final per-edge MLP, dst-major: B[d] once, A[s] fp8-gathered, tmp coalesced --
// wave per node; 4 edge slots x 16 lanes (8 channels per lane)
__global__ void k_edge_out_csr(const uint2* __restrict__ Au2, const uint4* __restrict__ Bu4,
                               const float* __restrict__ G,
                               const int* __restrict__ rowptr, const int* __restrict__ csr,
                               const int* __restrict__ batch,
                               const float* __restrict__ W2, const float* __restrict__ b2,
                               float* __restrict__ tmp, int n){
  int node = (blockIdx.x*blockDim.x + threadIdx.x) >> 6;
  int lane = threadIdx.x & 63;
  if (node >= n) return;
  int sub = lane >> 4;
  int l   = lane & 15;            // channels 8l .. 8l+7
  int p0 = rowptr[node];
  int deg2 = rowptr[node+1] - p0 - 1;      // excludes self loop
  if (deg2 <= 0) return;
  uint4 b = Bu4[(size_t)node*16 + l];      // B[d] bf16, shared by all edges of node
  float2 b01 = unpack_bf16(b.x), b23 = unpack_bf16(b.y);
  float2 b45 = unpack_bf16(b.z), b67 = unpack_bf16(b.w);
  float4 w0 = *(const float4*)&W2[8*l];
  float4 w1 = *(const float4*)&W2[8*l + 4];
  float b2v = b2[0];
  int rbase = p0 - node;          // rank base in self-loop-free CSR
  int rounds = (deg2 + 3) >> 2;
  // stage 0 prefetch
  int e = sub;
  bool vcur = e < deg2;
  int scur = csr[p0 + 1 + (vcur ? e : 0)];
  int gcur = batch[scur];
  uint2 acur = Au2[(size_t)scur*16 + l];
  for (int r = 0; r < rounds; ++r){
    int en = 4*(r+1) + sub;
    bool vn = en < deg2;
    int sn = csr[p0 + 1 + (vn ? en : 0)];
    int gn = batch[sn];
    uint2 anxt = acur;
    if (r + 1 < rounds) anxt = Au2[(size_t)sn*16 + l];
    // compute current edge
    const float* Gp = &G[gcur*128 + 8*l];
    float4 g0 = *(const float4*)Gp;
    float4 g1 = *(const float4*)(Gp + 4);
    floatx2 a01 = __builtin_amdgcn_cvt_pk_f32_fp8(acur.x, false);
    floatx2 a23 = __builtin_amdgcn_cvt_pk_f32_fp8(acur.x, true);
    floatx2 a45 = __builtin_amdgcn_cvt_pk_f32_fp8(acur.y, false);
    floatx2 a67 = __builtin_amdgcn_cvt_pk_f32_fp8(acur.y, true);
    float part;
    part = fmaxf(a01.x + b01.x + g0.x, 0.f) * w0.x;
    part = fmaf(fmaxf(a01.y + b01.y + g0.y, 0.f), w0.y, part);
    part = fmaf(fmaxf(a23.x + b23.x + g0.z, 0.f), w0.z, part);
    part = fmaf(fmaxf(a23.y + b23.y + g0.w, 0.f), w0.w, part);
    part = fmaf(fmaxf(a45.x + b45.x + g1.x, 0.f), w1.x, part);
    part = fmaf(fmaxf(a45.y + b45.y + g1.y, 0.f), w1.y, part);
    part = fmaf(fmaxf(a67.x + b67.x + g1.z, 0.f), w1.z, part);
    part = fmaf(fmaxf(a67.y + b67.y + g1.w, 0.f), w1.w, part);
#pragma unroll
    for (int mm = 1; mm < 16; mm <<= 1) part += __shfl_xor(part, mm, 64);
    if (l == 0 && vcur) tmp[rbase + 4*r + sub] = part + b2v;   // coalesced (CSR order)
    acur = anxt; vcur = vn; gcur = gn;
  }
}

// ---- out[i] = tmp[epos[i]] : coalesced read of epos + L2-resident gather ----
__global__ void k_remap(const float* __restrict__ tmp, const int* __restrict__ epos,
                        float* __restrict__ out, int e){
  int i = blockIdx.x*blockDim.x + threadIdx.x;
  if (i < e) out[i] = tmp[epos[i]];
}

extern "C" void kernel_launch(void* const* d_in, const int* in_sizes, int n_in,
                              void* d_out, int out_size, void* d_ws, size_t ws_size,
                              hipStream_t stream){
  const float* x     = (const float*)d_in[0];
  const int*   ei    = (const int*)d_in[1];
  const int*   batch = (const int*)d_in[2];
  const int N = in_sizes[2];
  const int E = in_sizes[1] / 2;
  const int* src = ei;
  const int* dst = ei + E;

  unsigned* W = (unsigned*)d_ws;
  const size_t N32 = (size_t)N * 32;
  const size_t N64 = (size_t)N * 64;
  // dword layout: [xl bf16: N32][xr: N64][hE: N64][hD: N64] | ints | gc/G/bsum/tmp
  unsigned short* xlh = (unsigned short*)W;          // N x 64 bf16
  float* xr = (float*)(W + N32);
  float* hE = (float*)(W + N32 + N64);
  float* hD = (float*)(W + N32 + 2*N64);
  // readout aliases (xl/xr/hE dead by then; hD untouched)
  unsigned short* Au16 = (unsigned short*)W;         // N x 128 fp8 (N32 dwords)
  unsigned* Bu = W + N32;                            // N x 64 dwords bf16 (aliases xr)
  int* rowptr = (int*)(W + N32 + 3*N64);             // N+2
  int* cursor = rowptr + (N + 2);                    // N
  int* csr    = cursor + N;                          // N + E
  int* epos   = csr + (N + E);                       // E
  float* gc   = (float*)(epos + E);                  // 8*64
  float* G    = gc + 512;                            // 8*128
  int* bsum   = (int*)(G + 1024);                    // ceil(N/256)
  float* tmp  = (float*)(bsum + 256);                // E floats (CSR-ordered results)

  const int NB = (N + 255) / 256;

  // ---- CSR build (once, reused by all 3 layers + edge MLP) ----
  hipMemsetAsync(cursor, 0, (size_t)N*4, stream);
  k_deg_count<<<(E+255)/256, 256, 0, stream>>>(dst, cursor, E);
  k_scan_a   <<<NB, 256, 0, stream>>>(cursor, rowptr, bsum, N);
  k_scan_b   <<<1, 256, 0, stream>>>(bsum, rowptr, NB, N);
  k_scan_c_selfloop<<<NB, 256, 0, stream>>>(rowptr, bsum, cursor, csr, gc, N);
  k_scatter  <<<(E+255)/256, 256, 0, stream>>>(src, dst, cursor, csr, epos, E);

  // ---- 3 GATv2 layers ----
  const float* h = x;
  float* hn = hD;
  for (int l = 0; l < 3; ++l){
    const float* Wl   = (const float*)d_in[3 + 9*l + 0];
    const float* bl   = (const float*)d_in[3 + 9*l + 1];
    const float* Wr   = (const float*)d_in[3 + 9*l + 2];
    const float* br   = (const float*)d_in[3 + 9*l + 3];
    const float* att  = (const float*)d_in[3 + 9*l + 4];
    const float* Wres = (const float*)d_in[3 + 9*l + 5];
    const float* bias = (const float*)d_in[3 + 9*l + 6];
    const float* lng  = (const float*)d_in[3 + 9*l + 7];
    const float* lnb  = (const float*)d_in[3 + 9*l + 8];
    if (l == 0)
      k_node_transform<32><<<(N+31)/32, 256, 0, stream>>>(h, Wl, bl, Wr, br, Wres, bias, xlh, xr, hn, N);
    else
      k_node_transform<64><<<(N+31)/32, 256, 0, stream>>>(h, Wl, bl, Wr, br, Wres, bias, xlh, xr, hn, N);
    k_gat_edge<<<(N+3)/4, 256, 0, stream>>>((const unsigned*)xlh, xr, att, lng, lnb, rowptr, csr, hn, N);
    h = hn;
    hn = (l == 0) ? hE : hD;   // L0->hD, L1->hE, L2->hD ; final node_repr = hD
  }

  // ---- readout ----
  const float* W1 = (const float*)d_in[30];
  const float* b1 = (const float*)d_in[31];
  const float* W2 = (const float*)d_in[32];
  const float* b2 = (const float*)d_in[33];

  int pool_waves = (N + 63) / 64;
  k_pool      <<<(pool_waves+3)/4, 256, 0, stream>>>(hD, batch, gc, N);
  k_graph_proj<<<1, 1024, 0, stream>>>(gc, W1, b1, G);
  k_node_proj <<<(N+31)/32, 256, 0, stream>>>(hD, W1, Au16, Bu, N);
  k_edge_out_csr<<<(N+3)/4, 256, 0, stream>>>((const uint2*)Au16, (const uint4*)Bu, G,
                                              rowptr, csr, batch, W2, b2, tmp, N);
  k_remap     <<<(E+255)/256, 256, 0, stream>>>(tmp, epos, (float*)d_out, E);
}